// Round 1
// baseline (1175.793 us; speedup 1.0000x reference)
//
#include <hip/hip_runtime.h>

// GAT forward, MI355X. Round 0: correct fp32 baseline.
// B=8, N=1024, F=256, O=128, H=8, HO=1024.
// ws layout (floats):
//   h_cat [B,N,HO]   @ 0          (8,388,608)
//   x     [B,N,HO]   @ 8388608    (8,388,608)
//   s1    [B*H,N]    @ 16777216   (65,536)
//   s2    [B*H,N]    @ 16842752   (65,536)
//   h2    [B*N,O]    @ 16908288   (1,048,576)
//   s1o   [B*N]      @ 17956864   (8,192)
//   s2o   [B*N]      @ 17965056   (8,192)
//   out2  [B*N,O]    @ 17973248   (1,048,576)
// total 19,021,824 floats = 76.1 MB

#define NN 1024
#define FF 256
#define OO 128
#define HH 8
#define HO 1024
#define NEGV -9.0e15f

__device__ __forceinline__ float lrelu(float x) { return fmaxf(x, 0.2f * x); }

// ---------------- generic 64x64 tiled fp32 GEMM ----------------
// C[.,c] (ldc) = A[.,k] (lda) @ B ; batch via blockIdx.z (strideA/strideC)
// mode 0: B row-major [K, Ncol], leading dim ldb
// mode 2: B = W_att packed [H,F,O]: B(k,c) = W[(c>>7)*F*O + k*O + (c&127)]
__global__ __launch_bounds__(256) void gemm64(
    const float* __restrict__ A, const float* __restrict__ Bm,
    float* __restrict__ C, int K, int lda, int ldb, int ldc,
    long strideA, long strideC, int mode)
{
    __shared__ float As[16][68];   // [k][m], row stride 68*4B = 17*16B (f4-aligned)
    __shared__ float Bs[16][68];   // [k][c]
    const int t = threadIdx.x;
    const int tx = t & 15, ty = t >> 4;
    const int c0 = blockIdx.x * 64, m0 = blockIdx.y * 64;
    A += (long)blockIdx.z * strideA;
    C += (long)blockIdx.z * strideC;
    float acc[4][4] = {};
    const int am = t >> 2, ak = (t & 3) * 4;
    const int bk = t >> 4, bc = (t & 15) * 4;
    for (int k0 = 0; k0 < K; k0 += 16) {
        float4 av = *(const float4*)(A + (long)(m0 + am) * lda + k0 + ak);
        As[ak + 0][am] = av.x; As[ak + 1][am] = av.y;
        As[ak + 2][am] = av.z; As[ak + 3][am] = av.w;
        float4 bv;
        if (mode == 0) {
            bv = *(const float4*)(Bm + (long)(k0 + bk) * ldb + c0 + bc);
        } else {
            int cg = c0 + bc;
            bv = *(const float4*)(Bm + (long)(cg >> 7) * (FF * OO) +
                                  (long)(k0 + bk) * OO + (cg & 127));
        }
        Bs[bk][bc + 0] = bv.x; Bs[bk][bc + 1] = bv.y;
        Bs[bk][bc + 2] = bv.z; Bs[bk][bc + 3] = bv.w;
        __syncthreads();
#pragma unroll
        for (int kk = 0; kk < 16; kk++) {
            float4 a4 = *(const float4*)&As[kk][ty * 4];
            float4 b4 = *(const float4*)&Bs[kk][tx * 4];
            float ar[4] = {a4.x, a4.y, a4.z, a4.w};
            float br[4] = {b4.x, b4.y, b4.z, b4.w};
#pragma unroll
            for (int i = 0; i < 4; i++)
#pragma unroll
                for (int j = 0; j < 4; j++) acc[i][j] += ar[i] * br[j];
        }
        __syncthreads();
    }
#pragma unroll
    for (int i = 0; i < 4; i++) {
        float4 v = make_float4(acc[i][0], acc[i][1], acc[i][2], acc[i][3]);
        *(float4*)(C + (long)(m0 + ty * 4 + i) * ldc + c0 + tx * 4) = v;
    }
}

// ---------------- s1/s2 for layer 0 (8 heads, h_cat rows of 1024) -----------
// wave per (b,n) row; lane l covers cols [16l,16l+16) -> head hh = l>>3
__global__ __launch_bounds__(256) void dots8(
    const float* __restrict__ h_cat, const float* __restrict__ a_src,
    const float* __restrict__ a_dst, float* __restrict__ s1,
    float* __restrict__ s2)
{
    int w = blockIdx.x * 4 + (threadIdx.x >> 6);   // 0..8191 = b*N+n
    int lane = threadIdx.x & 63;
    int b = w >> 10, n = w & 1023;
    const float* row = h_cat + (long)w * HO + lane * 16;
    int hh = lane >> 3;
    const float* asr = a_src + hh * OO + (lane & 7) * 16;
    const float* adr = a_dst + hh * OO + (lane & 7) * 16;
    float p1 = 0.f, p2 = 0.f;
#pragma unroll
    for (int q = 0; q < 4; q++) {
        float4 hv = ((const float4*)row)[q];
        float4 av = ((const float4*)asr)[q];
        float4 dv = ((const float4*)adr)[q];
        p1 += hv.x * av.x + hv.y * av.y + hv.z * av.z + hv.w * av.w;
        p2 += hv.x * dv.x + hv.y * dv.y + hv.z * dv.z + hv.w * dv.w;
    }
#pragma unroll
    for (int m = 1; m < 8; m <<= 1) {
        p1 += __shfl_xor(p1, m);
        p2 += __shfl_xor(p2, m);
    }
    if ((lane & 7) == 0) {
        int idx = (b * HH + hh) * NN + n;
        s1[idx] = p1;
        s2[idx] = p2;
    }
}

// ---------------- s1/s2 for layer 1 (1 head, rows of 128) -------------------
__global__ __launch_bounds__(256) void dots1(
    const float* __restrict__ h2, const float* __restrict__ ao_src,
    const float* __restrict__ ao_dst, float* __restrict__ s1o,
    float* __restrict__ s2o)
{
    int r = blockIdx.x * 4 + (threadIdx.x >> 6);
    int l = threadIdx.x & 63;
    float a = h2[(long)r * OO + l], c = h2[(long)r * OO + 64 + l];
    float p1 = a * ao_src[l] + c * ao_src[64 + l];
    float p2 = a * ao_dst[l] + c * ao_dst[64 + l];
#pragma unroll
    for (int m = 1; m < 64; m <<= 1) {
        p1 += __shfl_xor(p1, m);
        p2 += __shfl_xor(p2, m);
    }
    if (l == 0) { s1o[r] = p1; s2o[r] = p2; }
}

// ---------------- fused masked-softmax attention + PV -----------------------
// logits e[i,j] = lrelu(s1[i]+s2[j]) masked by adj[b,i,j]; out[i,:] = sum_j w*h[j,:]
// block: 32 i-rows for one (b,hh); 256 thr: il = t>>3 (i), sub = t&7 (8 per i)
__global__ __launch_bounds__(256) void attn(
    const float* __restrict__ s1g, const float* __restrict__ s2g,
    const float* __restrict__ hmat, const int* __restrict__ adj,
    float* __restrict__ outp, int Hheads, int hRowStride, int outRowStride,
    int doElu)
{
    int bh = blockIdx.y;
    int b = bh / Hheads, hh = bh % Hheads;
    int i0 = blockIdx.x * 32;
    const float* s1r = s1g + (long)bh * NN;
    const float* s2r = s2g + (long)bh * NN;
    const float* hb = hmat + (long)b * NN * hRowStride + hh * OO;
    const int* adjb = adj + (long)b * NN * NN;
    float* outb = outp + (long)b * NN * outRowStride + hh * OO;

    __shared__ float s2s[NN];
    __shared__ float mpart[32][8];
    __shared__ float lpart[32][8];
    __shared__ float mi[32];
    __shared__ float rli[32];
    __shared__ float hs[32][128];
    __shared__ float wls[32][33];   // +1 pad: reads stride 33 -> no 8-way bank conflict

    int t = threadIdx.x;
    for (int j = t; j < NN; j += 256) s2s[j] = s2r[j];
    __syncthreads();

    int il = t >> 3, sub = t & 7;
    int gi = i0 + il;
    float s1v = s1r[gi];
    const int* adjrow = adjb + (long)gi * NN;

    // pass 1: online softmax stats (max, sumexp) per i
    float m = -INFINITY, l = 0.f;
    for (int j = sub; j < NN; j += 8) {
        float e = lrelu(s1v + s2s[j]);
        float xv = (adjrow[j] > 0) ? e : NEGV;
        float mn = fmaxf(m, xv);
        l = l * __expf(m - mn) + __expf(xv - mn);
        m = mn;
    }
    mpart[il][sub] = m;
    lpart[il][sub] = l;
    __syncthreads();
    if (sub == 0) {
        float M = mpart[il][0], L = lpart[il][0];
#pragma unroll
        for (int q = 1; q < 8; q++) {
            float m2 = mpart[il][q], l2 = lpart[il][q];
            float mn = fmaxf(M, m2);
            L = L * __expf(M - mn) + l2 * __expf(m2 - mn);
            M = mn;
        }
        mi[il] = M;
        rli[il] = 1.0f / L;
    }
    __syncthreads();

    // pass 2: accumulate out[i, ob..ob+15] = sum_j w(i,j) * h[j, ob..]
    float acc[16] = {};
    int ob = sub * 16;
    float mI = mi[il], rlI = rli[il];
    for (int j0 = 0; j0 < NN; j0 += 32) {
        {   // stage h tile [32][128]: thread loads row il, cols [ob, ob+16)
            const float* hp = hb + (long)(j0 + il) * hRowStride + ob;
            float4* dst = (float4*)&hs[il][ob];
            const float4* src = (const float4*)hp;
            dst[0] = src[0]; dst[1] = src[1]; dst[2] = src[2]; dst[3] = src[3];
        }
        {   // stage w tile [32][32]: thread computes 4 entries of row il
#pragma unroll
            for (int q = 0; q < 4; q++) {
                int jj = (sub * 4) + q;
                int j = j0 + jj;
                float e = lrelu(s1v + s2s[j]);
                float xv = (adjrow[j] > 0) ? e : NEGV;
                wls[il][jj] = __expf(xv - mI) * rlI;
            }
        }
        __syncthreads();
#pragma unroll 8
        for (int jj = 0; jj < 32; jj++) {
            float w = wls[il][jj];
            const float4* hv = (const float4*)&hs[jj][ob];
            float4 a0 = hv[0], a1 = hv[1], a2 = hv[2], a3 = hv[3];
            acc[0]  += w * a0.x; acc[1]  += w * a0.y;
            acc[2]  += w * a0.z; acc[3]  += w * a0.w;
            acc[4]  += w * a1.x; acc[5]  += w * a1.y;
            acc[6]  += w * a1.z; acc[7]  += w * a1.w;
            acc[8]  += w * a2.x; acc[9]  += w * a2.y;
            acc[10] += w * a2.z; acc[11] += w * a2.w;
            acc[12] += w * a3.x; acc[13] += w * a3.y;
            acc[14] += w * a3.z; acc[15] += w * a3.w;
        }
        __syncthreads();
    }
    if (doElu) {
#pragma unroll
        for (int q = 0; q < 16; q++) {
            float v = acc[q];
            acc[q] = (v > 0.f) ? v : (__expf(v) - 1.0f);
        }
    }
    float* orow = outb + (long)gi * outRowStride + ob;
#pragma unroll
    for (int q = 0; q < 4; q++) {
        ((float4*)orow)[q] = make_float4(acc[q * 4 + 0], acc[q * 4 + 1],
                                         acc[q * 4 + 2], acc[q * 4 + 3]);
    }
}

// ---------------- fused: y = x@lin_w.T + lin_b + out2; z = relu(y@ln_w.T + ln_b)
// block: 32 rows x 128 cols; il = t>>3, ob = (t&7)*16
__global__ __launch_bounds__(256) void final_kernel(
    const float* __restrict__ x, const float* __restrict__ out2,
    const float* __restrict__ lin_w, const float* __restrict__ lin_b,
    const float* __restrict__ ln_w, const float* __restrict__ ln_b,
    float* __restrict__ out)
{
    __shared__ float xs[32][36];    // [i][k]
    __shared__ float lt[32][132];   // [k][c], transposed lin_w tile
    __shared__ float ys[32][132];   // [i][c], row stride 132*4B = 33*16B aligned
    int t = threadIdx.x;
    int il = t >> 3, ob = (t & 7) * 16;
    long row0 = (long)blockIdx.x * 32;
    float acc[16] = {};
    for (int k0 = 0; k0 < HO; k0 += 32) {
        {
            int kk = (t & 7) * 4;
            float4 v = *(const float4*)(x + (row0 + il) * HO + k0 + kk);
            xs[il][kk] = v.x; xs[il][kk + 1] = v.y;
            xs[il][kk + 2] = v.z; xs[il][kk + 3] = v.w;
        }
#pragma unroll
        for (int q = 0; q < 4; q++) {
            int idx = t * 4 + q;
            int c = idx >> 3, k4 = (idx & 7) * 4;
            float4 v = *(const float4*)(lin_w + (long)c * HO + k0 + k4);
            lt[k4][c] = v.x; lt[k4 + 1][c] = v.y;
            lt[k4 + 2][c] = v.z; lt[k4 + 3][c] = v.w;
        }
        __syncthreads();
#pragma unroll 8
        for (int kk = 0; kk < 32; kk++) {
            float xv = xs[il][kk];
            const float4* lv = (const float4*)&lt[kk][ob];
            float4 b0 = lv[0], b1 = lv[1], b2 = lv[2], b3 = lv[3];
            acc[0]  += xv * b0.x; acc[1]  += xv * b0.y;
            acc[2]  += xv * b0.z; acc[3]  += xv * b0.w;
            acc[4]  += xv * b1.x; acc[5]  += xv * b1.y;
            acc[6]  += xv * b1.z; acc[7]  += xv * b1.w;
            acc[8]  += xv * b2.x; acc[9]  += xv * b2.y;
            acc[10] += xv * b2.z; acc[11] += xv * b2.w;
            acc[12] += xv * b3.x; acc[13] += xv * b3.y;
            acc[14] += xv * b3.z; acc[15] += xv * b3.w;
        }
        __syncthreads();
    }
    long row = row0 + il;
#pragma unroll
    for (int q = 0; q < 16; q++)
        acc[q] += lin_b[ob + q] + out2[row * OO + ob + q];
#pragma unroll
    for (int q = 0; q < 16; q++) ys[il][ob + q] = acc[q];
    __syncthreads();
    float zac[16];
#pragma unroll
    for (int jo = 0; jo < 16; jo++) {
        int c = ob + jo;
        const float4* wr = (const float4*)(ln_w + (long)c * OO);
        const float4* yr = (const float4*)&ys[il][0];
        float dot = 0.f;
#pragma unroll 8
        for (int k4 = 0; k4 < 32; k4++) {
            float4 w4 = wr[k4];
            float4 y4 = yr[k4];
            dot += w4.x * y4.x + w4.y * y4.y + w4.z * y4.z + w4.w * y4.w;
        }
        zac[jo] = fmaxf(dot + ln_b[c], 0.f);
    }
    float* orow = out + row * OO + ob;
#pragma unroll
    for (int q = 0; q < 4; q++)
        ((float4*)orow)[q] = make_float4(zac[q * 4 + 0], zac[q * 4 + 1],
                                         zac[q * 4 + 2], zac[q * 4 + 3]);
}

extern "C" void kernel_launch(void* const* d_in, const int* in_sizes, int n_in,
                              void* d_out, int out_size, void* d_ws, size_t ws_size,
                              hipStream_t stream)
{
    const float* inputs = (const float*)d_in[0];   // [8,1024,256]
    const int*   adj    = (const int*)d_in[1];     // [8,1024,1024]
    // d_in[2] = mask (unused)
    const float* W_att  = (const float*)d_in[3];   // [8,256,128]
    const float* a_src  = (const float*)d_in[4];   // [8,128]
    const float* a_dst  = (const float*)d_in[5];   // [8,128]
    const float* W_out  = (const float*)d_in[6];   // [1024,128]
    const float* ao_src = (const float*)d_in[7];   // [128]
    const float* ao_dst = (const float*)d_in[8];   // [128]
    const float* lin_w  = (const float*)d_in[9];   // [128,1024]
    const float* lin_b  = (const float*)d_in[10];  // [128]
    const float* ln_w   = (const float*)d_in[11];  // [128,128]
    const float* ln_b   = (const float*)d_in[12];  // [128]
    float* out = (float*)d_out;

    float* ws    = (float*)d_ws;
    float* h_cat = ws;
    float* x     = ws + 8388608;
    float* s1    = ws + 16777216;
    float* s2    = ws + 16842752;
    float* h2    = ws + 16908288;
    float* s1o   = ws + 17956864;
    float* s2o   = ws + 17965056;
    float* out2  = ws + 17973248;

    // 1. h_cat[b,n,h*O+o] = sum_f inputs[b,n,f] * W_att[h,f,o]
    gemm64<<<dim3(16, 16, 8), 256, 0, stream>>>(
        inputs, W_att, h_cat, FF, FF, 0, HO,
        (long)NN * FF, (long)NN * HO, 2);
    // 2. s1/s2 per (b,h,n)
    dots8<<<2048, 256, 0, stream>>>(h_cat, a_src, a_dst, s1, s2);
    // 3. layer-0 attention -> x = elu(att@h), head-concat layout
    attn<<<dim3(32, 64), 256, 0, stream>>>(
        s1, s2, h_cat, adj, x, HH, HO, HO, 1);
    // 4. h2 = x @ W_out   [8192,1024]@[1024,128]
    gemm64<<<dim3(2, 128, 1), 256, 0, stream>>>(
        x, W_out, h2, HO, HO, OO, OO, 0, 0, 0);
    // 5. s1o/s2o per (b,n)
    dots1<<<2048, 256, 0, stream>>>(h2, ao_src, ao_dst, s1o, s2o);
    // 6. layer-1 attention -> out2 = att@h2 (no elu)
    attn<<<dim3(32, 8), 256, 0, stream>>>(
        s1o, s2o, h2, adj, out2, 1, OO, OO, 0);
    // 7. out = relu((x@lin_w.T + lin_b + out2) @ ln_w.T + ln_b)
    final_kernel<<<256, 256, 0, stream>>>(
        x, out2, lin_w, lin_b, ln_w, ln_b, out);
}

// Round 2
// 507.470 us; speedup vs baseline: 2.3170x; 2.3170x over previous
//
#include <hip/hip_runtime.h>

// GAT forward, MI355X. Round 1: MFMA everywhere except final_kernel.
// B=8, N=1024, F=256, O=128, H=8, HO=1024, BH=64.
//
// Pipeline:
//   transpose_cvt : W_att [H,F,O] -> W_attTb bf16 [H,O,F]; W_out [HO,O] -> W_outTb bf16 [O,HO]
//   gemmT  (x2)   : D[o][n] = sum_k AT[o][k]*B[n][k] (bf16 MFMA 16x16x32, fp32 acc)
//                   writes C as bf16 h^T AND fuses s1/s2 = h . a_{src,dst} in epilogue
//   attn_mfma(x2) : single-pass softmax (no max-sub; logits bounded) + MFMA PV,
//                   A = e^ computed in-register, B = h^T bf16 loaded direct from global
//   final_kernel  : unchanged fp32 (round-2 target)
//
// ws layout (floats):
//   x    [8,1024,1024] @ 0          (8,388,608)
//   out2 [8192,128]    @ 8388608    (1,048,576)
//   s1   [64,1024]     @ 9437184    s2 @ 9502720   (65,536 each)
//   s1o  [8192]        @ 9568256    s2o @ 9576448  (8,192 each)
// ushort (bf16) region @ float offset 9584640:
//   h_catTb [64,128,1024] @ 0        (8,388,608)
//   h2Tb    [8,128,1024]  @ 8388608  (1,048,576)
//   W_attTb [8,128,256]   @ 9437184  (262,144)
//   W_outTb [128,1024]    @ 9699328  (131,072)
// total ~58 MB (round-0 used 76 MB OK)

#define NN 1024
#define FF 256
#define OO 128
#define HH 8
#define HO 1024

typedef __attribute__((ext_vector_type(8))) short short8;
typedef __attribute__((ext_vector_type(4))) float floatx4;

__device__ __forceinline__ ushort f2b(float f) {
    union { float f; unsigned u; } v; v.f = f;
    unsigned r = v.u + 0x7FFFu + ((v.u >> 16) & 1u);   // RNE
    return (ushort)(r >> 16);
}
__device__ __forceinline__ float b2f(ushort u) {
    union { unsigned u; float f; } v; v.u = ((unsigned)u) << 16;
    return v.f;
}

// ---------------- transpose + bf16 cvt: dst[z][c][r] = src[z][r][c] ----------
__global__ __launch_bounds__(256) void transpose_cvt(
    const float* __restrict__ src, ushort* __restrict__ dst, int R, int C)
{
    __shared__ float tile[64][65];
    int r0 = blockIdx.x * 64, c0 = blockIdx.y * 64;
    src += (long)blockIdx.z * R * C;
    dst += (long)blockIdx.z * R * C;
    int t = threadIdx.x;
    int lr = t >> 4, lc = (t & 15) * 4;
#pragma unroll
    for (int p = 0; p < 4; p++) {
        float4 v = *(const float4*)(src + (long)(r0 + p * 16 + lr) * C + c0 + lc);
        tile[p * 16 + lr][lc] = v.x; tile[p * 16 + lr][lc + 1] = v.y;
        tile[p * 16 + lr][lc + 2] = v.z; tile[p * 16 + lr][lc + 3] = v.w;
    }
    __syncthreads();
    int c = t >> 2, rq = (t & 3) * 16;
    union { ushort s[16]; uint4 q[2]; } u;
#pragma unroll
    for (int k = 0; k < 16; k++) u.s[k] = f2b(tile[rq + k][c]);
    uint4* dp = (uint4*)(dst + (long)(c0 + c) * R + r0 + rq);
    dp[0] = u.q[0]; dp[1] = u.q[1];
}

// ---------------- bf16 MFMA "NT" GEMM with transposed output + fused dots ---
// D[m=o][n] = sum_k AT[o][k] * Bf[n][k];  AT bf16 [O][K] (per head), Bf fp32.
// Writes Cb bf16 [bh][O][NN] and s1/s2[bh][n] = sum_o D[o][n]*a{1,2}[o].
__global__ __launch_bounds__(256) void gemmT(
    const ushort* __restrict__ AT, const float* __restrict__ Bf,
    ushort* __restrict__ Cb, float* __restrict__ s1, float* __restrict__ s2,
    const float* __restrict__ a1g, const float* __restrict__ a2g,
    int K, int Hh)
{
    int t = threadIdx.x;
    int wave = t >> 6, lane = t & 63;
    int quad = lane >> 4, l16 = lane & 15;
    int bh = blockIdx.y;
    int hh = bh % Hh, b = bh / Hh;
    int n0w = blockIdx.x * 64 + wave * 16;

    const ushort* A = AT + (long)hh * OO * K;
    const float* brow = Bf + ((long)b * NN + n0w + l16) * K;

    floatx4 acc[8];
    floatx4 zero = {0.f, 0.f, 0.f, 0.f};
#pragma unroll
    for (int mt = 0; mt < 8; mt++) acc[mt] = zero;

    for (int k0 = 0; k0 < K; k0 += 32) {
        int kb = k0 + quad * 8;
        float4 b0 = *(const float4*)(brow + kb);
        float4 b1 = *(const float4*)(brow + kb + 4);
        short8 bfr;
        bfr[0] = (short)f2b(b0.x); bfr[1] = (short)f2b(b0.y);
        bfr[2] = (short)f2b(b0.z); bfr[3] = (short)f2b(b0.w);
        bfr[4] = (short)f2b(b1.x); bfr[5] = (short)f2b(b1.y);
        bfr[6] = (short)f2b(b1.z); bfr[7] = (short)f2b(b1.w);
#pragma unroll
        for (int mt = 0; mt < 8; mt++) {
            short8 af = *(const short8*)(A + (long)(mt * 16 + l16) * K + kb);
            acc[mt] = __builtin_amdgcn_mfma_f32_16x16x32_bf16(af, bfr, acc[mt], 0, 0, 0);
        }
    }

    // fused s1/s2: wave holds all 128 o for its 16 n columns
    const float* a1 = a1g + hh * OO;
    const float* a2 = a2g + hh * OO;
    float sp1 = 0.f, sp2 = 0.f;
#pragma unroll
    for (int mt = 0; mt < 8; mt++) {
        float4 v1 = *(const float4*)(a1 + mt * 16 + quad * 4);
        float4 v2 = *(const float4*)(a2 + mt * 16 + quad * 4);
        sp1 += acc[mt][0] * v1.x + acc[mt][1] * v1.y + acc[mt][2] * v1.z + acc[mt][3] * v1.w;
        sp2 += acc[mt][0] * v2.x + acc[mt][1] * v2.y + acc[mt][2] * v2.z + acc[mt][3] * v2.w;
    }
    sp1 += __shfl_xor(sp1, 16); sp1 += __shfl_xor(sp1, 32);
    sp2 += __shfl_xor(sp2, 16); sp2 += __shfl_xor(sp2, 32);
    if (lane < 16) {
        s1[(long)bh * NN + n0w + l16] = sp1;
        s2[(long)bh * NN + n0w + l16] = sp2;
    }

    // store h^T bf16
    ushort* cb = Cb + (long)bh * OO * NN;
#pragma unroll
    for (int mt = 0; mt < 8; mt++) {
#pragma unroll
        for (int reg = 0; reg < 4; reg++) {
            int o = mt * 16 + quad * 4 + reg;
            cb[(long)o * NN + n0w + l16] = f2b(acc[mt][reg]);
        }
    }
}

// ---------------- single-pass masked-softmax attention + MFMA PV ------------
// e^(i,j) = adj ? exp(lrelu(s1_i+s2_j)) : 0 (logits bounded, no max-sub needed)
// out[i,:] = (sum_j e^ * h[j,:]) / (sum_j e^).  A = e^ in-register, B = h^T bf16.
__global__ __launch_bounds__(256) void attn_mfma(
    const float* __restrict__ s1g, const float* __restrict__ s2g,
    const ushort* __restrict__ hTb, const int* __restrict__ adj,
    float* __restrict__ outp, int Hh, int outStride, int doElu)
{
    __shared__ float s2s[NN];
    int t = threadIdx.x;
    int wave = t >> 6, lane = t & 63;
    int quad = lane >> 4, l16 = lane & 15;
    int bh = blockIdx.y;
    int hh = bh % Hh, b = bh / Hh;
    int i0 = blockIdx.x * 128 + wave * 32;

    const float* s2r = s2g + (long)bh * NN;
    for (int j = t; j < NN; j += 256) s2s[j] = s2r[j];
    __syncthreads();

    float s1a = s1g[(long)bh * NN + i0 + l16];
    float s1b = s1g[(long)bh * NN + i0 + 16 + l16];
    const int* adjra = adj + (long)b * NN * NN + (long)(i0 + l16) * NN;
    const int* adjrb = adjra + 16 * NN;
    const ushort* hT = hTb + (long)bh * OO * NN;

    floatx4 acc0[8], acc1[8];
    floatx4 zero = {0.f, 0.f, 0.f, 0.f};
#pragma unroll
    for (int ot = 0; ot < 8; ot++) { acc0[ot] = zero; acc1[ot] = zero; }
    float Lp0 = 0.f, Lp1 = 0.f;

    for (int j0 = 0; j0 < NN; j0 += 32) {
        int kb = j0 + quad * 8;
        float4 sA = *(const float4*)(s2s + kb);
        float4 sB = *(const float4*)(s2s + kb + 4);
        int4 ia0 = *(const int4*)(adjra + kb);
        int4 ia1 = *(const int4*)(adjra + kb + 4);
        int4 ib0 = *(const int4*)(adjrb + kb);
        int4 ib1 = *(const int4*)(adjrb + kb + 4);
        float se[8] = {sA.x, sA.y, sA.z, sA.w, sB.x, sB.y, sB.z, sB.w};
        int ma[8] = {ia0.x, ia0.y, ia0.z, ia0.w, ia1.x, ia1.y, ia1.z, ia1.w};
        int mb[8] = {ib0.x, ib0.y, ib0.z, ib0.w, ib1.x, ib1.y, ib1.z, ib1.w};
        short8 afa, afb;
#pragma unroll
        for (int e = 0; e < 8; e++) {
            float ea = s1a + se[e]; ea = fmaxf(ea, 0.2f * ea);
            float eb = s1b + se[e]; eb = fmaxf(eb, 0.2f * eb);
            float wa = (ma[e] > 0) ? __expf(ea) : 0.f;
            float wb = (mb[e] > 0) ? __expf(eb) : 0.f;
            ushort ua = f2b(wa), ub = f2b(wb);
            afa[e] = (short)ua; afb[e] = (short)ub;
            Lp0 += b2f(ua); Lp1 += b2f(ub);
        }
#pragma unroll
        for (int ot = 0; ot < 8; ot++) {
            short8 bf = *(const short8*)(hT + (long)(ot * 16 + l16) * NN + kb);
            acc0[ot] = __builtin_amdgcn_mfma_f32_16x16x32_bf16(afa, bf, acc0[ot], 0, 0, 0);
            acc1[ot] = __builtin_amdgcn_mfma_f32_16x16x32_bf16(afb, bf, acc1[ot], 0, 0, 0);
        }
    }

    Lp0 += __shfl_xor(Lp0, 16); Lp0 += __shfl_xor(Lp0, 32);
    Lp1 += __shfl_xor(Lp1, 16); Lp1 += __shfl_xor(Lp1, 32);
    float rinv0 = 1.0f / Lp0;   // lane holds 1/L for row (lane&15) of its i-tile
    float rinv1 = 1.0f / Lp1;

    float* ob = outp + (long)b * NN * outStride + hh * OO;
#pragma unroll
    for (int it = 0; it < 2; it++) {
        float rv = it ? rinv1 : rinv0;
        floatx4* ac = it ? acc1 : acc0;
#pragma unroll
        for (int reg = 0; reg < 4; reg++) {
            float linv = __shfl(rv, quad * 4 + reg);
            int row = i0 + it * 16 + quad * 4 + reg;
            float* orow = ob + (long)row * outStride + l16;
#pragma unroll
            for (int ot = 0; ot < 8; ot++) {
                float v = ac[ot][reg] * linv;
                if (doElu) v = (v > 0.f) ? v : (__expf(v) - 1.0f);
                orow[ot * 16] = v;
            }
        }
    }
}

// ---------------- fused: y = x@lin_w.T + lin_b + out2; z = relu(y@ln_w.T + ln_b)
__global__ __launch_bounds__(256) void final_kernel(
    const float* __restrict__ x, const float* __restrict__ out2,
    const float* __restrict__ lin_w, const float* __restrict__ lin_b,
    const float* __restrict__ ln_w, const float* __restrict__ ln_b,
    float* __restrict__ out)
{
    __shared__ float xs[32][36];
    __shared__ float lt[32][132];
    __shared__ float ys[32][132];
    int t = threadIdx.x;
    int il = t >> 3, ob = (t & 7) * 16;
    long row0 = (long)blockIdx.x * 32;
    float acc[16] = {};
    for (int k0 = 0; k0 < HO; k0 += 32) {
        {
            int kk = (t & 7) * 4;
            float4 v = *(const float4*)(x + (row0 + il) * HO + k0 + kk);
            xs[il][kk] = v.x; xs[il][kk + 1] = v.y;
            xs[il][kk + 2] = v.z; xs[il][kk + 3] = v.w;
        }
#pragma unroll
        for (int q = 0; q < 4; q++) {
            int idx = t * 4 + q;
            int c = idx >> 3, k4 = (idx & 7) * 4;
            float4 v = *(const float4*)(lin_w + (long)c * HO + k0 + k4);
            lt[k4][c] = v.x; lt[k4 + 1][c] = v.y;
            lt[k4 + 2][c] = v.z; lt[k4 + 3][c] = v.w;
        }
        __syncthreads();
#pragma unroll 8
        for (int kk = 0; kk < 32; kk++) {
            float xv = xs[il][kk];
            const float4* lv = (const float4*)&lt[kk][ob];
            float4 b0 = lv[0], b1 = lv[1], b2 = lv[2], b3 = lv[3];
            acc[0]  += xv * b0.x; acc[1]  += xv * b0.y;
            acc[2]  += xv * b0.z; acc[3]  += xv * b0.w;
            acc[4]  += xv * b1.x; acc[5]  += xv * b1.y;
            acc[6]  += xv * b1.z; acc[7]  += xv * b1.w;
            acc[8]  += xv * b2.x; acc[9]  += xv * b2.y;
            acc[10] += xv * b2.z; acc[11] += xv * b2.w;
            acc[12] += xv * b3.x; acc[13] += xv * b3.y;
            acc[14] += xv * b3.z; acc[15] += xv * b3.w;
        }
        __syncthreads();
    }
    long row = row0 + il;
#pragma unroll
    for (int q = 0; q < 16; q++)
        acc[q] += lin_b[ob + q] + out2[row * OO + ob + q];
#pragma unroll
    for (int q = 0; q < 16; q++) ys[il][ob + q] = acc[q];
    __syncthreads();
    float zac[16];
#pragma unroll
    for (int jo = 0; jo < 16; jo++) {
        int c = ob + jo;
        const float4* wr = (const float4*)(ln_w + (long)c * OO);
        const float4* yr = (const float4*)&ys[il][0];
        float dot = 0.f;
#pragma unroll 8
        for (int k4 = 0; k4 < 32; k4++) {
            float4 w4 = wr[k4];
            float4 y4 = yr[k4];
            dot += w4.x * y4.x + w4.y * y4.y + w4.z * y4.z + w4.w * y4.w;
        }
        zac[jo] = fmaxf(dot + ln_b[c], 0.f);
    }
    float* orow = out + row * OO + ob;
#pragma unroll
    for (int q = 0; q < 4; q++)
        ((float4*)orow)[q] = make_float4(zac[q * 4 + 0], zac[q * 4 + 1],
                                         zac[q * 4 + 2], zac[q * 4 + 3]);
}

extern "C" void kernel_launch(void* const* d_in, const int* in_sizes, int n_in,
                              void* d_out, int out_size, void* d_ws, size_t ws_size,
                              hipStream_t stream)
{
    const float* inputs = (const float*)d_in[0];   // [8,1024,256]
    const int*   adj    = (const int*)d_in[1];     // [8,1024,1024]
    const float* W_att  = (const float*)d_in[3];   // [8,256,128]
    const float* a_src  = (const float*)d_in[4];   // [8,128]
    const float* a_dst  = (const float*)d_in[5];   // [8,128]
    const float* W_out  = (const float*)d_in[6];   // [1024,128]
    const float* ao_src = (const float*)d_in[7];   // [128]
    const float* ao_dst = (const float*)d_in[8];   // [128]
    const float* lin_w  = (const float*)d_in[9];   // [128,1024]
    const float* lin_b  = (const float*)d_in[10];  // [128]
    const float* ln_w   = (const float*)d_in[11];  // [128,128]
    const float* ln_b   = (const float*)d_in[12];  // [128]
    float* out = (float*)d_out;

    float* ws   = (float*)d_ws;
    float* x    = ws;
    float* out2 = ws + 8388608;
    float* s1   = ws + 9437184;
    float* s2   = ws + 9502720;
    float* s1o  = ws + 9568256;
    float* s2o  = ws + 9576448;
    ushort* ub      = (ushort*)(ws + 9584640);
    ushort* h_catTb = ub;
    ushort* h2Tb    = ub + 8388608;
    ushort* W_attTb = ub + 9437184;
    ushort* W_outTb = ub + 9699328;

    // 0. weight transposes -> bf16
    transpose_cvt<<<dim3(4, 2, 8), 256, 0, stream>>>(W_att, W_attTb, FF, OO);
    transpose_cvt<<<dim3(16, 2, 1), 256, 0, stream>>>(W_out, W_outTb, HO, OO);
    // 1. h^T = (inputs @ W_att)^T per (b,h), bf16; fused s1/s2
    gemmT<<<dim3(16, 64), 256, 0, stream>>>(
        W_attTb, inputs, h_catTb, s1, s2, a_src, a_dst, FF, HH);
    // 2. layer-0 attention -> x = elu(att@h), row-major [B,N,HO]
    attn_mfma<<<dim3(8, 64), 256, 0, stream>>>(
        s1, s2, h_catTb, adj, x, HH, HO, 1);
    // 3. h2^T = (x @ W_out)^T per b, bf16; fused s1o/s2o
    gemmT<<<dim3(16, 8), 256, 0, stream>>>(
        W_outTb, x, h2Tb, s1o, s2o, ao_src, ao_dst, HO, 1);
    // 4. layer-1 attention -> out2 (no elu)
    attn_mfma<<<dim3(8, 8), 256, 0, stream>>>(
        s1o, s2o, h2Tb, adj, out2, 1, OO, 0);
    // 5. out = relu((x@lin_w.T + lin_b + out2) @ ln_w.T + ln_b)
    final_kernel<<<256, 256, 0, stream>>>(
        x, out2, lin_w, lin_b, ln_w, ln_b, out);
}

// Round 3
// 360.351 us; speedup vs baseline: 3.2629x; 1.4083x over previous
//
#include <hip/hip_runtime.h>

// GAT forward, MI355X. Round 2: final_kernel -> MFMA; x stored bf16.
// B=8, N=1024, F=256, O=128, H=8, HO=1024, BH=64.
//
// Pipeline:
//   transpose_cvt : W_att [H,F,O] -> bf16 [H,O,F]; W_out [HO,O] -> bf16 [O,HO]
//   cvt_bf16      : lin_w, ln_w -> bf16 (already [out,k] NT layout)
//   gemmT  (x2)   : h^T = (act @ W)^T bf16, fused s1/s2 dots (MFMA 16x16x32)
//   attn_mfma(x2) : single-pass softmax (bounded logits, no max-sub) + MFMA PV
//                   layer-0 writes x bf16, layer-1 writes out2 fp32
//   final_mfma    : y = x@lin_w.T+lin_b+out2 (MFMA, y->LDS bf16),
//                   out = relu(y@ln_w.T+ln_b) (MFMA)
//
// ws floats:
//   out2 [8192,128] @ 0        (1,048,576)
//   s1 @ 1048576  s2 @ 1114112 (65,536 each)
//   s1o @ 1179648 s2o @ 1187840 (8,192 each)
// ushort region @ float offset 1196032 (byte 4,784,128; 16B aligned):
//   x_b     [8,1024,1024] @ 0         (8,388,608)
//   h_catTb [64,128,1024] @ 8388608   (8,388,608)
//   h2Tb    [8,128,1024]  @ 16777216  (1,048,576)
//   W_attTb [8,128,256]   @ 17825792  (262,144)
//   W_outTb [128,1024]    @ 18087936  (131,072)
//   lin_wb  [128,1024]    @ 18219008  (131,072)
//   ln_wb   [128,128]     @ 18350080  (16,384)
// total ~41.5 MB (round-0 used 76 MB OK)

#define NN 1024
#define FF 256
#define OO 128
#define HH 8
#define HO 1024

typedef __attribute__((ext_vector_type(8))) short short8;
typedef __attribute__((ext_vector_type(4))) float floatx4;

__device__ __forceinline__ ushort f2b(float f) {
    union { float f; unsigned u; } v; v.f = f;
    unsigned r = v.u + 0x7FFFu + ((v.u >> 16) & 1u);   // RNE
    return (ushort)(r >> 16);
}
__device__ __forceinline__ float b2f(ushort u) {
    union { unsigned u; float f; } v; v.u = ((unsigned)u) << 16;
    return v.f;
}

// ---------------- transpose + bf16 cvt: dst[z][c][r] = src[z][r][c] ----------
__global__ __launch_bounds__(256) void transpose_cvt(
    const float* __restrict__ src, ushort* __restrict__ dst, int R, int C)
{
    __shared__ float tile[64][65];
    int r0 = blockIdx.x * 64, c0 = blockIdx.y * 64;
    src += (long)blockIdx.z * R * C;
    dst += (long)blockIdx.z * R * C;
    int t = threadIdx.x;
    int lr = t >> 4, lc = (t & 15) * 4;
#pragma unroll
    for (int p = 0; p < 4; p++) {
        float4 v = *(const float4*)(src + (long)(r0 + p * 16 + lr) * C + c0 + lc);
        tile[p * 16 + lr][lc] = v.x; tile[p * 16 + lr][lc + 1] = v.y;
        tile[p * 16 + lr][lc + 2] = v.z; tile[p * 16 + lr][lc + 3] = v.w;
    }
    __syncthreads();
    int c = t >> 2, rq = (t & 3) * 16;
    union { ushort s[16]; uint4 q[2]; } u;
#pragma unroll
    for (int k = 0; k < 16; k++) u.s[k] = f2b(tile[rq + k][c]);
    uint4* dp = (uint4*)(dst + (long)(c0 + c) * R + r0 + rq);
    dp[0] = u.q[0]; dp[1] = u.q[1];
}

// ---------------- elementwise fp32 -> bf16 (8 el/thread) --------------------
__global__ __launch_bounds__(256) void cvt_bf16(
    const float* __restrict__ src, ushort* __restrict__ dst)
{
    long i = ((long)blockIdx.x * 256 + threadIdx.x) * 8;
    float4 v0 = *(const float4*)(src + i);
    float4 v1 = *(const float4*)(src + i + 4);
    union { ushort s[8]; uint4 q; } u;
    u.s[0] = f2b(v0.x); u.s[1] = f2b(v0.y); u.s[2] = f2b(v0.z); u.s[3] = f2b(v0.w);
    u.s[4] = f2b(v1.x); u.s[5] = f2b(v1.y); u.s[6] = f2b(v1.z); u.s[7] = f2b(v1.w);
    *(uint4*)(dst + i) = u.q;
}

// ---------------- bf16 MFMA "NT" GEMM with transposed output + fused dots ---
// D[m=o][n] = sum_k AT[o][k] * B[n][k];  AT bf16 [O][K] per head.
// B either fp32 (Bf) or bf16 (Bb) selected by bBf. Writes Cb bf16 [bh][O][NN]
// and s1/s2[bh][n] = sum_o D[o][n]*a{1,2}[o].
__global__ __launch_bounds__(256) void gemmT(
    const ushort* __restrict__ AT, const float* __restrict__ Bf,
    const ushort* __restrict__ Bb,
    ushort* __restrict__ Cb, float* __restrict__ s1, float* __restrict__ s2,
    const float* __restrict__ a1g, const float* __restrict__ a2g,
    int K, int Hh, int bBf)
{
    int t = threadIdx.x;
    int wave = t >> 6, lane = t & 63;
    int quad = lane >> 4, l16 = lane & 15;
    int bh = blockIdx.y;
    int hh = bh % Hh, b = bh / Hh;
    int n0w = blockIdx.x * 64 + wave * 16;

    const ushort* A = AT + (long)hh * OO * K;
    const float* browf = Bf + ((long)b * NN + n0w + l16) * K;
    const ushort* browb = Bb + ((long)b * NN + n0w + l16) * K;

    floatx4 acc[8];
    floatx4 zero = {0.f, 0.f, 0.f, 0.f};
#pragma unroll
    for (int mt = 0; mt < 8; mt++) acc[mt] = zero;

    for (int k0 = 0; k0 < K; k0 += 32) {
        int kb = k0 + quad * 8;
        short8 bfr;
        if (bBf) {
            bfr = *(const short8*)(browb + kb);
        } else {
            float4 b0 = *(const float4*)(browf + kb);
            float4 b1 = *(const float4*)(browf + kb + 4);
            bfr[0] = (short)f2b(b0.x); bfr[1] = (short)f2b(b0.y);
            bfr[2] = (short)f2b(b0.z); bfr[3] = (short)f2b(b0.w);
            bfr[4] = (short)f2b(b1.x); bfr[5] = (short)f2b(b1.y);
            bfr[6] = (short)f2b(b1.z); bfr[7] = (short)f2b(b1.w);
        }
#pragma unroll
        for (int mt = 0; mt < 8; mt++) {
            short8 af = *(const short8*)(A + (long)(mt * 16 + l16) * K + kb);
            acc[mt] = __builtin_amdgcn_mfma_f32_16x16x32_bf16(af, bfr, acc[mt], 0, 0, 0);
        }
    }

    // fused s1/s2: wave holds all 128 o for its 16 n columns
    const float* a1 = a1g + hh * OO;
    const float* a2 = a2g + hh * OO;
    float sp1 = 0.f, sp2 = 0.f;
#pragma unroll
    for (int mt = 0; mt < 8; mt++) {
        float4 v1 = *(const float4*)(a1 + mt * 16 + quad * 4);
        float4 v2 = *(const float4*)(a2 + mt * 16 + quad * 4);
        sp1 += acc[mt][0] * v1.x + acc[mt][1] * v1.y + acc[mt][2] * v1.z + acc[mt][3] * v1.w;
        sp2 += acc[mt][0] * v2.x + acc[mt][1] * v2.y + acc[mt][2] * v2.z + acc[mt][3] * v2.w;
    }
    sp1 += __shfl_xor(sp1, 16); sp1 += __shfl_xor(sp1, 32);
    sp2 += __shfl_xor(sp2, 16); sp2 += __shfl_xor(sp2, 32);
    if (lane < 16) {
        s1[(long)bh * NN + n0w + l16] = sp1;
        s2[(long)bh * NN + n0w + l16] = sp2;
    }

    // store h^T bf16
    ushort* cb = Cb + (long)bh * OO * NN;
#pragma unroll
    for (int mt = 0; mt < 8; mt++) {
#pragma unroll
        for (int reg = 0; reg < 4; reg++) {
            int o = mt * 16 + quad * 4 + reg;
            cb[(long)o * NN + n0w + l16] = f2b(acc[mt][reg]);
        }
    }
}

// ---------------- single-pass masked-softmax attention + MFMA PV ------------
// e^(i,j) = adj ? exp(lrelu(s1_i+s2_j)) : 0 (logits bounded, no max-sub needed)
// out[i,:] = (sum_j e^ * h[j,:]) / (sum_j e^).  A = e^ in-register, B = h^T bf16.
// writeBf: out -> outb (bf16) else outf (fp32).
__global__ __launch_bounds__(256) void attn_mfma(
    const float* __restrict__ s1g, const float* __restrict__ s2g,
    const ushort* __restrict__ hTb, const int* __restrict__ adj,
    float* __restrict__ outf, ushort* __restrict__ outb,
    int Hh, int outStride, int doElu, int writeBf)
{
    __shared__ float s2s[NN];
    int t = threadIdx.x;
    int wave = t >> 6, lane = t & 63;
    int quad = lane >> 4, l16 = lane & 15;
    int bh = blockIdx.y;
    int hh = bh % Hh, b = bh / Hh;
    int i0 = blockIdx.x * 128 + wave * 32;

    const float* s2r = s2g + (long)bh * NN;
    for (int j = t; j < NN; j += 256) s2s[j] = s2r[j];
    __syncthreads();

    float s1a = s1g[(long)bh * NN + i0 + l16];
    float s1b = s1g[(long)bh * NN + i0 + 16 + l16];
    const int* adjra = adj + (long)b * NN * NN + (long)(i0 + l16) * NN;
    const int* adjrb = adjra + 16 * NN;
    const ushort* hT = hTb + (long)bh * OO * NN;

    floatx4 acc0[8], acc1[8];
    floatx4 zero = {0.f, 0.f, 0.f, 0.f};
#pragma unroll
    for (int ot = 0; ot < 8; ot++) { acc0[ot] = zero; acc1[ot] = zero; }
    float Lp0 = 0.f, Lp1 = 0.f;

    for (int j0 = 0; j0 < NN; j0 += 32) {
        int kb = j0 + quad * 8;
        float4 sA = *(const float4*)(s2s + kb);
        float4 sB = *(const float4*)(s2s + kb + 4);
        int4 ia0 = *(const int4*)(adjra + kb);
        int4 ia1 = *(const int4*)(adjra + kb + 4);
        int4 ib0 = *(const int4*)(adjrb + kb);
        int4 ib1 = *(const int4*)(adjrb + kb + 4);
        float se[8] = {sA.x, sA.y, sA.z, sA.w, sB.x, sB.y, sB.z, sB.w};
        int ma[8] = {ia0.x, ia0.y, ia0.z, ia0.w, ia1.x, ia1.y, ia1.z, ia1.w};
        int mb[8] = {ib0.x, ib0.y, ib0.z, ib0.w, ib1.x, ib1.y, ib1.z, ib1.w};
        short8 afa, afb;
#pragma unroll
        for (int e = 0; e < 8; e++) {
            float ea = s1a + se[e]; ea = fmaxf(ea, 0.2f * ea);
            float eb = s1b + se[e]; eb = fmaxf(eb, 0.2f * eb);
            float wa = (ma[e] > 0) ? __expf(ea) : 0.f;
            float wb = (mb[e] > 0) ? __expf(eb) : 0.f;
            ushort ua = f2b(wa), ub = f2b(wb);
            afa[e] = (short)ua; afb[e] = (short)ub;
            Lp0 += b2f(ua); Lp1 += b2f(ub);
        }
#pragma unroll
        for (int ot = 0; ot < 8; ot++) {
            short8 bf = *(const short8*)(hT + (long)(ot * 16 + l16) * NN + kb);
            acc0[ot] = __builtin_amdgcn_mfma_f32_16x16x32_bf16(afa, bf, acc0[ot], 0, 0, 0);
            acc1[ot] = __builtin_amdgcn_mfma_f32_16x16x32_bf16(afb, bf, acc1[ot], 0, 0, 0);
        }
    }

    Lp0 += __shfl_xor(Lp0, 16); Lp0 += __shfl_xor(Lp0, 32);
    Lp1 += __shfl_xor(Lp1, 16); Lp1 += __shfl_xor(Lp1, 32);
    float rinv0 = 1.0f / Lp0;
    float rinv1 = 1.0f / Lp1;

#pragma unroll
    for (int it = 0; it < 2; it++) {
        float rv = it ? rinv1 : rinv0;
        floatx4* ac = it ? acc1 : acc0;
#pragma unroll
        for (int reg = 0; reg < 4; reg++) {
            float linv = __shfl(rv, quad * 4 + reg);
            int row = i0 + it * 16 + quad * 4 + reg;
            if (writeBf) {
                ushort* orow = outb + (long)b * NN * outStride + hh * OO +
                               (long)row * outStride + l16;
#pragma unroll
                for (int ot = 0; ot < 8; ot++) {
                    float v = ac[ot][reg] * linv;
                    if (doElu) v = (v > 0.f) ? v : (__expf(v) - 1.0f);
                    orow[ot * 16] = f2b(v);
                }
            } else {
                float* orow = outf + (long)b * NN * outStride + hh * OO +
                              (long)row * outStride + l16;
#pragma unroll
                for (int ot = 0; ot < 8; ot++) {
                    float v = ac[ot][reg] * linv;
                    if (doElu) v = (v > 0.f) ? v : (__expf(v) - 1.0f);
                    orow[ot * 16] = v;
                }
            }
        }
    }
}

// ---------------- final: y = x@lin_w.T+lin_b+out2; out = relu(y@ln_w.T+ln_b)
// MFMA both GEMMs; 32 rows/block, 4 waves each 2 m-tiles x 2 n-tiles.
__global__ __launch_bounds__(256) void final_mfma(
    const ushort* __restrict__ xb, const float* __restrict__ out2,
    const ushort* __restrict__ lwb, const float* __restrict__ lin_b,
    const ushort* __restrict__ nwb, const float* __restrict__ ln_b,
    float* __restrict__ out)
{
    __shared__ ushort ys[32][136];   // +8 pad: quad-rows spread banks
    int t = threadIdx.x;
    int wave = t >> 6, lane = t & 63;
    int quad = lane >> 4, l16 = lane & 15;
    long row0 = (long)blockIdx.x * 32;
    int n0 = wave * 32;

    floatx4 zero = {0.f, 0.f, 0.f, 0.f};
    floatx4 acc[2][2];
#pragma unroll
    for (int mt = 0; mt < 2; mt++)
#pragma unroll
        for (int nt = 0; nt < 2; nt++) acc[mt][nt] = zero;

    // GEMM1: y[m][c] = sum_k x[m][k] * lin_w[c][k]
    for (int k0 = 0; k0 < HO; k0 += 32) {
        int kb = k0 + quad * 8;
        short8 a0 = *(const short8*)(xb + (row0 + l16) * HO + kb);
        short8 a1 = *(const short8*)(xb + (row0 + 16 + l16) * HO + kb);
        short8 b0 = *(const short8*)(lwb + (long)(n0 + l16) * HO + kb);
        short8 b1 = *(const short8*)(lwb + (long)(n0 + 16 + l16) * HO + kb);
        acc[0][0] = __builtin_amdgcn_mfma_f32_16x16x32_bf16(a0, b0, acc[0][0], 0, 0, 0);
        acc[0][1] = __builtin_amdgcn_mfma_f32_16x16x32_bf16(a0, b1, acc[0][1], 0, 0, 0);
        acc[1][0] = __builtin_amdgcn_mfma_f32_16x16x32_bf16(a1, b0, acc[1][0], 0, 0, 0);
        acc[1][1] = __builtin_amdgcn_mfma_f32_16x16x32_bf16(a1, b1, acc[1][1], 0, 0, 0);
    }

    // epilogue 1: y += lin_b + out2 -> LDS bf16 (A-layout for GEMM2)
#pragma unroll
    for (int nt = 0; nt < 2; nt++) {
        int col = n0 + nt * 16 + l16;
        float lb = lin_b[col];
#pragma unroll
        for (int mt = 0; mt < 2; mt++) {
#pragma unroll
            for (int reg = 0; reg < 4; reg++) {
                int row = mt * 16 + quad * 4 + reg;
                float v = acc[mt][nt][reg] + lb + out2[(row0 + row) * OO + col];
                ys[row][col] = f2b(v);
            }
        }
    }
    __syncthreads();

    // GEMM2: out[m][o] = relu(sum_c y[m][c] * ln_w[o][c] + ln_b[o])
    floatx4 acc2[2][2];
#pragma unroll
    for (int mt = 0; mt < 2; mt++)
#pragma unroll
        for (int nt = 0; nt < 2; nt++) acc2[mt][nt] = zero;

#pragma unroll
    for (int k0 = 0; k0 < OO; k0 += 32) {
        int kb = k0 + quad * 8;
        short8 a0 = *(const short8*)&ys[l16][kb];
        short8 a1 = *(const short8*)&ys[16 + l16][kb];
        short8 b0 = *(const short8*)(nwb + (long)(n0 + l16) * OO + kb);
        short8 b1 = *(const short8*)(nwb + (long)(n0 + 16 + l16) * OO + kb);
        acc2[0][0] = __builtin_amdgcn_mfma_f32_16x16x32_bf16(a0, b0, acc2[0][0], 0, 0, 0);
        acc2[0][1] = __builtin_amdgcn_mfma_f32_16x16x32_bf16(a0, b1, acc2[0][1], 0, 0, 0);
        acc2[1][0] = __builtin_amdgcn_mfma_f32_16x16x32_bf16(a1, b0, acc2[1][0], 0, 0, 0);
        acc2[1][1] = __builtin_amdgcn_mfma_f32_16x16x32_bf16(a1, b1, acc2[1][1], 0, 0, 0);
    }

#pragma unroll
    for (int nt = 0; nt < 2; nt++) {
        int col = n0 + nt * 16 + l16;
        float nb = ln_b[col];
#pragma unroll
        for (int mt = 0; mt < 2; mt++) {
#pragma unroll
            for (int reg = 0; reg < 4; reg++) {
                int row = mt * 16 + quad * 4 + reg;
                out[(row0 + row) * OO + col] = fmaxf(acc2[mt][nt][reg] + nb, 0.f);
            }
        }
    }
}

extern "C" void kernel_launch(void* const* d_in, const int* in_sizes, int n_in,
                              void* d_out, int out_size, void* d_ws, size_t ws_size,
                              hipStream_t stream)
{
    const float* inputs = (const float*)d_in[0];   // [8,1024,256]
    const int*   adj    = (const int*)d_in[1];     // [8,1024,1024]
    const float* W_att  = (const float*)d_in[3];   // [8,256,128]
    const float* a_src  = (const float*)d_in[4];   // [8,128]
    const float* a_dst  = (const float*)d_in[5];   // [8,128]
    const float* W_out  = (const float*)d_in[6];   // [1024,128]
    const float* ao_src = (const float*)d_in[7];   // [128]
    const float* ao_dst = (const float*)d_in[8];   // [128]
    const float* lin_w  = (const float*)d_in[9];   // [128,1024]
    const float* lin_b  = (const float*)d_in[10];  // [128]
    const float* ln_w   = (const float*)d_in[11];  // [128,128]
    const float* ln_b   = (const float*)d_in[12];  // [128]
    float* out = (float*)d_out;

    float* ws   = (float*)d_ws;
    float* out2 = ws;
    float* s1   = ws + 1048576;
    float* s2   = ws + 1114112;
    float* s1o  = ws + 1179648;
    float* s2o  = ws + 1187840;
    ushort* ub      = (ushort*)(ws + 1196032);
    ushort* x_b     = ub;
    ushort* h_catTb = ub + 8388608;
    ushort* h2Tb    = ub + 16777216;
    ushort* W_attTb = ub + 17825792;
    ushort* W_outTb = ub + 18087936;
    ushort* lin_wb  = ub + 18219008;
    ushort* ln_wb   = ub + 18350080;

    // 0. weight conversions
    transpose_cvt<<<dim3(4, 2, 8), 256, 0, stream>>>(W_att, W_attTb, FF, OO);
    transpose_cvt<<<dim3(16, 2, 1), 256, 0, stream>>>(W_out, W_outTb, HO, OO);
    cvt_bf16<<<64, 256, 0, stream>>>(lin_w, lin_wb);
    cvt_bf16<<<8, 256, 0, stream>>>(ln_w, ln_wb);
    // 1. h^T = (inputs @ W_att)^T per (b,h), bf16; fused s1/s2
    gemmT<<<dim3(16, 64), 256, 0, stream>>>(
        W_attTb, inputs, (const ushort*)nullptr, h_catTb, s1, s2,
        a_src, a_dst, FF, HH, 0);
    // 2. layer-0 attention -> x = elu(att@h) bf16, row-major [B,N,HO]
    attn_mfma<<<dim3(8, 64), 256, 0, stream>>>(
        s1, s2, h_catTb, adj, (float*)nullptr, x_b, HH, HO, 1, 1);
    // 3. h2^T = (x @ W_out)^T per b, bf16; fused s1o/s2o
    gemmT<<<dim3(16, 8), 256, 0, stream>>>(
        W_outTb, (const float*)nullptr, x_b, h2Tb, s1o, s2o,
        ao_src, ao_dst, HO, 1, 1);
    // 4. layer-1 attention -> out2 fp32 (no elu)
    attn_mfma<<<dim3(8, 8), 256, 0, stream>>>(
        s1o, s2o, h2Tb, adj, out2, (ushort*)nullptr, 1, OO, 0, 0);
    // 5. out = relu((x@lin_w.T + lin_b + out2) @ ln_w.T + ln_b)
    final_mfma<<<256, 256, 0, stream>>>(
        x_b, out2, lin_wb, lin_b, ln_wb, ln_b, out);
}